// Round 5
// baseline (1306.811 us; speedup 1.0000x reference)
//
#include <hip/hip_runtime.h>
#include <hip/hip_fp16.h>

#define RELU_NEG_SLOPE 0.2f

typedef _Float16 half8 __attribute__((ext_vector_type(8)));
typedef float f32x4 __attribute__((ext_vector_type(4)));

__device__ __forceinline__ float leaky(float e) {
    return (e > 0.f) ? e : RELU_NEG_SLOPE * e;
}

__device__ __forceinline__ float elu1(float x) {
    return (x > 0.f) ? x : (__expf(x) - 1.f);
}

// ---------------------------------------------------------------------------
// All scratch in __device__ globals (zero-init .bss), NOT the poisoned
// workspace (validated rounds 2-4: graph-replay + rocprof safe).
// Self-resetting state (no zeroing pass ever):
//   g_cnt[d]  : zeroed by K4 (last consumer) after reading.
//   g_grp[g]  : zeroed by the finisher block that consumed it.
// Everything else is fully rewritten before being read each iteration.
// N=10000 <= 16384; deg <= 64 (Poisson(16): P(deg>64) ~ 1e-20).
// ---------------------------------------------------------------------------
#define MAXN 16384
#define MAXPAD 16384

__device__ __align__(256) int            g_cnt[MAXN];
__device__ __align__(256) int            g_grp[MAXN / 16 + 16];
__device__ __align__(256) unsigned short g_ell[MAXN * 64];
__device__ __align__(256) __half         g_proj1p[(size_t)4 * MAXPAD * 128];
__device__ __align__(256) __half         g_hbufh[(size_t)MAXPAD * 512];
__device__ __align__(256) __half         g_W2t[64 * 512];
__device__ __align__(256) __half         g_proj2h[MAXN * 64];
__device__ __align__(256) float          g_as1[MAXN * 8];
__device__ __align__(256) float          g_an1[MAXN * 8];
__device__ __align__(256) float          g_as2[MAXN];
__device__ __align__(256) float          g_an2[MAXN];

// ---------------------------------------------------------------------------
// K1: fused ELL scatter + W2 transpose (blocks [0,nscat)) + layer-1 MFMA
// GEMM (the rest). Staging-free (identical to round-2/4 verified version):
//   - A: direct fp32 float4 loads from x + in-register RTN fp16 convert.
//   - B: per-block LDS transpose of W1[h] (32KB coalesced read -> fp16 B^T
//     tile, row stride 132 halves).
// C written PERMUTED into 4 head-pair slabs (each 2.57 MB -> fits one XCD
// L2): g_proj1p[(h>>1)*slabN + n*128 + (h&1)*64 + f], slabN = Mpad*128.
// Epilogue: fused alpha1; stores guarded by N.
// ---------------------------------------------------------------------------
__global__ __launch_bounds__(256) void k1_scatter_gemm1(
    const int* __restrict__ edges, int E0,
    const float* __restrict__ W2, int t2, int nscat,
    const float4* __restrict__ x4, const float* __restrict__ W1,
    const float* __restrict__ a1, int N, int slabN) {
    __shared__ __half Bs[64 * 132];        // B^T tile, padded stride
    if (blockIdx.x < nscat) {
        int i = blockIdx.x * 256 + threadIdx.x;
        if (i < 2 * E0) {
            int s = edges[i];
            int d = (i < E0) ? edges[E0 + i] : edges[i - E0];
            int pos = atomicAdd(&g_cnt[d], 1);
            g_ell[(d << 6) + pos] = (unsigned short)s;
        } else if (i < 2 * E0 + t2) {
            int j = i - 2 * E0;
            int f = j & 63;
            int d = j >> 6;
            g_W2t[f * 512 + d] = __float2half(W2[j]);
        }
        return;
    }
    int bid2 = blockIdx.x - nscat;
    const int h = bid2 & 7;
    const int by = bid2 >> 3;

    // stage W1[h] (128x64 fp32, f-contiguous) -> Bs[f*132 + d] fp16
    {
        const float4* W1h = (const float4*)W1 + h * 2048;
        int t = threadIdx.x;
#pragma unroll
        for (int r = 0; r < 8; r++) {
            int j4 = t + r * 256;          // float4 index: 4 consecutive f
            float4 w = W1h[j4];
            int f = (j4 << 2) & 63;
            int d = j4 >> 4;
            Bs[(f + 0) * 132 + d] = __float2half(w.x);
            Bs[(f + 1) * 132 + d] = __float2half(w.y);
            Bs[(f + 2) * 132 + d] = __float2half(w.z);
            Bs[(f + 3) * 132 + d] = __float2half(w.w);
        }
    }
    __syncthreads();

    const int lane = threadIdx.x & 63;
    const int wave = threadIdx.x >> 6;
    const int q = lane >> 4;
    const int l15 = lane & 15;
    const int mrow = by * 64 + wave * 16;

    int arow = mrow + l15;
    if (arow >= N) arow = N - 1;           // pad rows: clamp (values unused)
    const float4* Ar = x4 + (size_t)arow * 32;

    f32x4 acc[4] = {{0.f, 0.f, 0.f, 0.f}, {0.f, 0.f, 0.f, 0.f},
                    {0.f, 0.f, 0.f, 0.f}, {0.f, 0.f, 0.f, 0.f}};
#pragma unroll
    for (int ks = 0; ks < 4; ks++) {
        float4 a0 = Ar[ks * 8 + q * 2];
        float4 a1v = Ar[ks * 8 + q * 2 + 1];
        half8 av;
        av[0] = (_Float16)a0.x; av[1] = (_Float16)a0.y;
        av[2] = (_Float16)a0.z; av[3] = (_Float16)a0.w;
        av[4] = (_Float16)a1v.x; av[5] = (_Float16)a1v.y;
        av[6] = (_Float16)a1v.z; av[7] = (_Float16)a1v.w;
#pragma unroll
        for (int t = 0; t < 4; t++) {
            half8 bv = *(const half8*)(Bs + (t * 16 + l15) * 132 + q * 8 + ks * 32);
            acc[t] = __builtin_amdgcn_mfma_f32_16x16x32_f16(av, bv, acc[t], 0, 0, 0);
        }
    }

    __half* Cs = g_proj1p + (size_t)(h >> 1) * slabN + (h & 1) * 64;
    float asc[4], anc[4];
#pragma unroll
    for (int t = 0; t < 4; t++) {
        asc[t] = a1[h * 128 + t * 16 + l15];
        anc[t] = a1[h * 128 + 64 + t * 16 + l15];
    }
#pragma unroll
    for (int r = 0; r < 4; r++) {
        int mg = mrow + q * 4 + r;
        float ps = 0.f, pn = 0.f;
#pragma unroll
        for (int t = 0; t < 4; t++) {
            float v = acc[t][r];
            ps += v * asc[t];
            pn += v * anc[t];
            if (mg < N)
                Cs[(size_t)mg * 128 + t * 16 + l15] = __float2half(v);
        }
#pragma unroll
        for (int m = 8; m >= 1; m >>= 1) {
            ps += __shfl_xor(ps, m, 64);
            pn += __shfl_xor(pn, m, 64);
        }
        if (l15 == 0 && mg < N) {
            g_as1[mg * 8 + h] = ps;
            g_an1[mg * 8 + h] = pn;
        }
    }
}

// ---------------------------------------------------------------------------
// K2': layer-1 aggregation (hp-sliced, MLP-unrolled — verified round 4)
// + EMBEDDED layer-2 GEMM via the last-arriver pattern.
//
// Agg: hp = bid&3 pins each 2.57MB proj1p slab to XCDs {hp, hp+4} (round-3
// counter-proven: losing this costs FETCH 37->60MB, ~25us). 16 edges/step.
//
// Group protocol: a 16-node group is complete after its 16 blocks (4
// node-quads x 4 head-pairs) finish. Each block: hbuf stores ->
// __threadfence (release) -> __syncthreads -> thread0 atomicAdd(g_grp).
// The 16th arriver acquires and runs the 16-row K=512 gemm2 tile with its
// 4 waves split over output-column quadrants (round-3-verified phase-B
// body incl. LDS alpha2 cross-wave reduce). No dispatch-order assumption,
// no spinning; g_grp self-resets. Removes the K3 dispatch + boundary and
// overlaps gemm2 with the agg tail.
// ---------------------------------------------------------------------------
__global__ __launch_bounds__(256) void k2_agg1_gemm2(
    const float* __restrict__ a2, int N, int slabN, int nbp) {
    __shared__ float red[4][16][2];
    __shared__ int fin;
    int bid = blockIdx.x;
    int hp = bid & 3;                      // phase = head pair, XCD-interleaved
    int rem = bid >> 2;
    int wave = threadIdx.x >> 6;
    int lane = threadIdx.x & 63;
    int d = rem * 4 + wave;

    if (d < N) {
        const int sub = lane >> 3;             // edge slot 0..7
        const int inner = lane & 7;
        const int hh = inner >> 2;             // head within pair
        const int h = hp * 2 + hh;
        const int c16 = (inner & 3) * 16;      // halves c16..c16+15 of head

        int deg = g_cnt[d];
        const unsigned short* row = g_ell + (d << 6);
        float asd = g_as1[d * 8 + h];
        const __half* slab = g_proj1p + (size_t)hp * slabN;

        float acc[16];
#pragma unroll
        for (int i = 0; i < 16; i++) acc[i] = 0.f;
        float den = 0.f;
        if (sub == 0) {   // self-loop (s = d)
            float e = __expf(leaky(asd + g_an1[d * 8 + h]));
            const __half* p = slab + (size_t)d * 128 + hh * 64 + c16;
            half8 v0 = *(const half8*)p;
            half8 v1 = *(const half8*)(p + 8);
            den = e;
#pragma unroll
            for (int i = 0; i < 8; i++) {
                acc[i] = e * (float)v0[i];
                acc[8 + i] = e * (float)v1[i];
            }
        }
        for (int j0 = 0; j0 < deg; j0 += 16) {
            int ja = j0 + sub;
            int jb = ja + 8;
            int jca = (ja < deg) ? ja : (deg - 1);   // deg > 0 in this loop
            int jcb = (jb < deg) ? jb : (deg - 1);
            int sa = row[jca];
            int sb = row[jcb];
            float na = g_an1[sa * 8 + h];
            float nb = g_an1[sb * 8 + h];
            const __half* pa = slab + (size_t)sa * 128 + hh * 64 + c16;
            const __half* pb = slab + (size_t)sb * 128 + hh * 64 + c16;
            half8 va0 = *(const half8*)pa;
            half8 va1 = *(const half8*)(pa + 8);
            half8 vb0 = *(const half8*)pb;
            half8 vb1 = *(const half8*)(pb + 8);
            float ea = __expf(leaky(asd + na));
            float eb = __expf(leaky(asd + nb));
            if (ja >= deg) ea = 0.f;
            if (jb >= deg) eb = 0.f;
            den += ea + eb;
#pragma unroll
            for (int i = 0; i < 8; i++) {
                acc[i]     += ea * (float)va0[i] + eb * (float)vb0[i];
                acc[8 + i] += ea * (float)va1[i] + eb * (float)vb1[i];
            }
        }

        // combine the 8 edge-slot partials (lane l += l+32, l+16, l+8)
#pragma unroll
        for (int off = 32; off >= 8; off >>= 1) {
#pragma unroll
            for (int i = 0; i < 16; i++) acc[i] += __shfl_down(acc[i], off, 64);
            den += __shfl_down(den, off, 64);
        }

        if (sub == 0) {
            float r = 1.f / den;     // den > 0 (self-loop)
            half8 o0, o1;
#pragma unroll
            for (int i = 0; i < 8; i++) {
                o0[i] = (_Float16)elu1(acc[i] * r);
                o1[i] = (_Float16)elu1(acc[8 + i] * r);
            }
            __half* op = g_hbufh + (size_t)d * 512 + h * 64 + c16;
            *(half8*)op = o0;
            *(half8*)(op + 8) = o1;
        }
    }

    // ---- group completion protocol (all threads of every block) ----
    int grp = rem >> 2;
    int nrem = nbp - (grp << 2);
    if (nrem > 4) nrem = 4;
    int expected = nrem * 4;               // blocks in this group (16 typ.)
    __threadfence();                       // release hbuf stores device-wide
    __syncthreads();                       // all 4 waves done + fenced
    if (threadIdx.x == 0) {
        int old = atomicAdd(&g_grp[grp], 1);
        int f = (old == expected - 1);
        if (f) g_grp[grp] = 0;             // self-reset for next iteration
        fin = f;
    }
    __syncthreads();
    if (!fin) return;

    // ---- finisher: 16-row x 64-col layer-2 GEMM, K=512; wave = col quad ----
    __threadfence();                       // acquire: see peers' hbuf stores
    const int node0 = grp << 4;
    const int q = lane >> 4;
    const int l15 = lane & 15;
    int arow = node0 + l15;
    if (arow >= N) arow = N - 1;           // addr clamp (stores guarded)
    f32x4 acc2 = {0.f, 0.f, 0.f, 0.f};
    const __half* Ap = g_hbufh + (size_t)arow * 512 + q * 8;
    const __half* Bp = g_W2t + (size_t)(wave * 16 + l15) * 512 + q * 8;
#pragma unroll
    for (int ks = 0; ks < 16; ks++) {
        half8 av = *(const half8*)(Ap + ks * 32);
        half8 bv = *(const half8*)(Bp + ks * 32);
        acc2 = __builtin_amdgcn_mfma_f32_16x16x32_f16(av, bv, acc2, 0, 0, 0);
    }
    float asc = a2[wave * 16 + l15];
    float anc = a2[64 + wave * 16 + l15];
#pragma unroll
    for (int r = 0; r < 4; r++) {
        int mg = node0 + q * 4 + r;
        float v = acc2[r];
        float ps = v * asc, pn = v * anc;
#pragma unroll
        for (int m = 8; m >= 1; m >>= 1) {
            ps += __shfl_xor(ps, m, 64);
            pn += __shfl_xor(pn, m, 64);
        }
        if (mg < N)
            g_proj2h[(size_t)mg * 64 + wave * 16 + l15] = __float2half(v);
        if (l15 == 0) {
            red[wave][q * 4 + r][0] = ps;
            red[wave][q * 4 + r][1] = pn;
        }
    }
    __syncthreads();
    if (threadIdx.x < 16) {
        int mg = node0 + threadIdx.x;
        if (mg < N) {
            int i = threadIdx.x;
            g_as2[mg] = red[0][i][0] + red[1][i][0] + red[2][i][0] + red[3][i][0];
            g_an2[mg] = red[0][i][1] + red[1][i][1] + red[2][i][1] + red[3][i][1];
        }
    }
}

// ---------------------------------------------------------------------------
// K4: layer-2 aggregation (H=1): one wave per node; MLP-unrolled 32
// edges/step (verified round 4). fp16 proj (1.28MB, L2-resident); self-loop
// in writer lanes' epilogue; fp32 out via two float4.
// ALSO resets g_cnt[d]=0 for the next iteration (after reading deg).
// ---------------------------------------------------------------------------
__global__ __launch_bounds__(256) void agg_node_h1(float* __restrict__ out,
                                                   int N) {
    int d = blockIdx.x * 4 + (threadIdx.x >> 6);
    int lane = threadIdx.x & 63;
    if (d >= N) return;
    int sub = lane >> 3;                   // edge slot 0..7
    int inner = lane & 7;                  // 8-half chunk
    int deg = g_cnt[d];
    if (lane == 0) g_cnt[d] = 0;           // self-reset for next iteration
    const unsigned short* row = g_ell + (d << 6);
    float asd = g_as2[d];

    float acc[8];
#pragma unroll
    for (int i = 0; i < 8; i++) acc[i] = 0.f;
    float den = 0.f;
    for (int j0 = 0; j0 < deg; j0 += 32) {
        int jj[4], s[4];
        float en[4];
        half8 v[4];
#pragma unroll
        for (int g = 0; g < 4; g++) {
            jj[g] = j0 + g * 8 + sub;
            int jc = (jj[g] < deg) ? jj[g] : (deg - 1);  // deg > 0 here
            s[g] = row[jc];
        }
#pragma unroll
        for (int g = 0; g < 4; g++) en[g] = g_an2[s[g]];
#pragma unroll
        for (int g = 0; g < 4; g++)
            v[g] = *(const half8*)(g_proj2h + (size_t)s[g] * 64 + inner * 8);
#pragma unroll
        for (int g = 0; g < 4; g++) {
            float e = __expf(leaky(asd + en[g]));
            if (jj[g] >= deg) e = 0.f;
            den += e;
#pragma unroll
            for (int i = 0; i < 8; i++) acc[i] += e * (float)v[g][i];
        }
    }

#pragma unroll
    for (int off = 32; off >= 8; off >>= 1) {
#pragma unroll
        for (int i = 0; i < 8; i++) acc[i] += __shfl_down(acc[i], off, 64);
        den += __shfl_down(den, off, 64);
    }

    if (sub == 0) {
        // self-loop (s = d)
        float e = __expf(leaky(asd + g_an2[d]));
        half8 v = *(const half8*)(g_proj2h + (size_t)d * 64 + inner * 8);
        den += e;
#pragma unroll
        for (int i = 0; i < 8; i++) acc[i] += e * (float)v[i];
        float rden = 1.f / den;
        float4 r0, r1;
        r0.x = acc[0] * rden; r0.y = acc[1] * rden;
        r0.z = acc[2] * rden; r0.w = acc[3] * rden;
        r1.x = acc[4] * rden; r1.y = acc[5] * rden;
        r1.z = acc[6] * rden; r1.w = acc[7] * rden;
        float* op = out + (size_t)d * 64 + inner * 8;
        *(float4*)op = r0;
        *(float4*)(op + 4) = r1;
    }
}

extern "C" void kernel_launch(void* const* d_in, const int* in_sizes, int n_in,
                              void* d_out, int out_size, void* d_ws, size_t ws_size,
                              hipStream_t stream) {
    const float* x  = (const float*)d_in[0];
    const int* edges = (const int*)d_in[1];
    const float* W1 = (const float*)d_in[2];
    const float* a1 = (const float*)d_in[3];
    const float* W2 = (const float*)d_in[4];
    const float* a2 = (const float*)d_in[5];

    const int Din = 128, H1 = 8, Dmid = 512;
    const int N = in_sizes[0] / Din;       // 10000
    const int E0 = in_sizes[1] / 2;        // 80000
    const int Mpad = (N + 63) & ~63;       // pad rows for MFMA tiles
    const int slabN = Mpad * 128;          // halves per head-pair slab
    (void)d_ws; (void)ws_size;

    // ---- K1: ELL scatter + W2 transpose + layer-1 MFMA GEMM ----
    int t2 = Dmid * 64;                    // 32768 W2 elements
    int nscat = (2 * E0 + t2 + 255) / 256;
    int ngemm = H1 * (Mpad / 64);
    k1_scatter_gemm1<<<nscat + ngemm, 256, 0, stream>>>(
        edges, E0, W2, t2, nscat, (const float4*)x, W1, a1, N, slabN);

    // ---- K2': L2-blocked softmax-agg + ELU + last-arriver layer-2 GEMM ----
    int nbp = (N + 3) / 4;
    k2_agg1_gemm2<<<4 * nbp, 256, 0, stream>>>(a2, N, slabN, nbp);

    // ---- K4: layer-2 aggregation + g_cnt self-reset ----
    agg_node_h1<<<(N + 3) / 4, 256, 0, stream>>>((float*)d_out, N);
}

// Round 6
// 138.415 us; speedup vs baseline: 9.4412x; 9.4412x over previous
//
#include <hip/hip_runtime.h>
#include <hip/hip_fp16.h>

#define RELU_NEG_SLOPE 0.2f

typedef _Float16 half8 __attribute__((ext_vector_type(8)));
typedef float f32x4 __attribute__((ext_vector_type(4)));

__device__ __forceinline__ float leaky(float e) {
    return (e > 0.f) ? e : RELU_NEG_SLOPE * e;
}

__device__ __forceinline__ float elu1(float x) {
    return (x > 0.f) ? x : (__expf(x) - 1.f);
}

// ---------------------------------------------------------------------------
// All scratch in __device__ globals (zero-init .bss), NOT the poisoned
// workspace (validated rounds 2-4: graph-replay + rocprof safe).
// g_cnt is self-resetting: K4 (last consumer) writes cnt[d]=0 after
// reading, so every iteration starts from zeros with no zeroing pass.
// Everything else is fully rewritten before being read each iteration.
// N=10000 <= 16384; deg <= 64 (Poisson(16): P(deg>64) ~ 1e-20).
// NOTE (rounds 1+5): cross-XCD visibility primitives (grid.sync,
// per-block __threadfence) cost ~µs each on gfx950 — dispatch boundaries
// are the CHEAP way to get device-wide visibility. Keep 4 dispatches.
// ---------------------------------------------------------------------------
#define MAXN 16384
#define MAXPAD 16384

__device__ __align__(256) int            g_cnt[MAXN];
__device__ __align__(256) unsigned short g_ell[MAXN * 64];
__device__ __align__(256) __half         g_proj1p[(size_t)4 * MAXPAD * 128];
__device__ __align__(256) __half         g_hbufh[(size_t)MAXPAD * 512];
__device__ __align__(256) __half         g_W2t[64 * 512];
__device__ __align__(256) __half         g_proj2h[MAXN * 64];
__device__ __align__(256) float          g_as1[MAXN * 8];
__device__ __align__(256) float          g_an1[MAXN * 8];
__device__ __align__(256) float          g_as2[MAXN];
__device__ __align__(256) float          g_an2[MAXN];

// ---------------------------------------------------------------------------
// K1: fused ELL scatter + W2 transpose (blocks [0,nscat)) + layer-1 MFMA
// GEMM (the rest). GEMM now processes a HEAD PAIR per block:
//   - A: direct fp32 float4 loads from x + in-register RTN fp16 convert,
//     loaded ONCE and reused for both heads' MFMA chains (halves A L2
//     traffic 40->20 MB and doubles MFMA density per block).
//   - B: per-block LDS transpose of W1[h0] and W1[h1] (2 x 32KB coalesced
//     read -> fp16 B^T tiles, row stride 132 halves; 33 KB LDS).
// C written PERMUTED into 4 head-pair slabs (each 2.57 MB -> fits one XCD
// L2): g_proj1p[hp*slabN + n*128 + hh*64 + f], slabN = Mpad*128.
// Epilogue: fused alpha1 per head; stores guarded by N.
// ---------------------------------------------------------------------------
__global__ __launch_bounds__(256) void k1_scatter_gemm1(
    const int* __restrict__ edges, int E0,
    const float* __restrict__ W2, int t2, int nscat,
    const float4* __restrict__ x4, const float* __restrict__ W1,
    const float* __restrict__ a1, int N, int slabN) {
    __shared__ __half Bs[2][64 * 132];     // B^T tiles (both heads), padded
    if (blockIdx.x < nscat) {
        int i = blockIdx.x * 256 + threadIdx.x;
        if (i < 2 * E0) {
            int s = edges[i];
            int d = (i < E0) ? edges[E0 + i] : edges[i - E0];
            int pos = atomicAdd(&g_cnt[d], 1);
            g_ell[(d << 6) + pos] = (unsigned short)s;
        } else if (i < 2 * E0 + t2) {
            int j = i - 2 * E0;
            int f = j & 63;
            int d = j >> 6;
            g_W2t[f * 512 + d] = __float2half(W2[j]);
        }
        return;
    }
    int bid2 = blockIdx.x - nscat;
    const int hp = bid2 & 3;
    const int by = bid2 >> 2;

    // stage W1[hp*2+hh] (128x64 fp32, f-contiguous) -> Bs[hh][f*132+d] fp16
#pragma unroll
    for (int hh = 0; hh < 2; hh++) {
        const float4* W1h = (const float4*)W1 + (hp * 2 + hh) * 2048;
        int t = threadIdx.x;
#pragma unroll
        for (int r = 0; r < 8; r++) {
            int j4 = t + r * 256;          // float4 index: 4 consecutive f
            float4 w = W1h[j4];
            int f = (j4 << 2) & 63;
            int d = j4 >> 4;
            Bs[hh][(f + 0) * 132 + d] = __float2half(w.x);
            Bs[hh][(f + 1) * 132 + d] = __float2half(w.y);
            Bs[hh][(f + 2) * 132 + d] = __float2half(w.z);
            Bs[hh][(f + 3) * 132 + d] = __float2half(w.w);
        }
    }
    __syncthreads();

    const int lane = threadIdx.x & 63;
    const int wave = threadIdx.x >> 6;
    const int q = lane >> 4;
    const int l15 = lane & 15;
    const int mrow = by * 64 + wave * 16;

    int arow = mrow + l15;
    if (arow >= N) arow = N - 1;           // pad rows: clamp (values unused)
    const float4* Ar = x4 + (size_t)arow * 32;

    f32x4 acc[2][4];
#pragma unroll
    for (int hh = 0; hh < 2; hh++)
#pragma unroll
        for (int t = 0; t < 4; t++) acc[hh][t] = {0.f, 0.f, 0.f, 0.f};
#pragma unroll
    for (int ks = 0; ks < 4; ks++) {
        float4 a0 = Ar[ks * 8 + q * 2];
        float4 a1v = Ar[ks * 8 + q * 2 + 1];
        half8 av;
        av[0] = (_Float16)a0.x; av[1] = (_Float16)a0.y;
        av[2] = (_Float16)a0.z; av[3] = (_Float16)a0.w;
        av[4] = (_Float16)a1v.x; av[5] = (_Float16)a1v.y;
        av[6] = (_Float16)a1v.z; av[7] = (_Float16)a1v.w;
#pragma unroll
        for (int hh = 0; hh < 2; hh++) {
#pragma unroll
            for (int t = 0; t < 4; t++) {
                half8 bv = *(const half8*)(&Bs[hh][(t * 16 + l15) * 132 + q * 8 + ks * 32]);
                acc[hh][t] = __builtin_amdgcn_mfma_f32_16x16x32_f16(av, bv, acc[hh][t], 0, 0, 0);
            }
        }
    }

#pragma unroll
    for (int hh = 0; hh < 2; hh++) {
        const int h = hp * 2 + hh;
        __half* Cs = g_proj1p + (size_t)hp * slabN + hh * 64;
        float asc[4], anc[4];
#pragma unroll
        for (int t = 0; t < 4; t++) {
            asc[t] = a1[h * 128 + t * 16 + l15];
            anc[t] = a1[h * 128 + 64 + t * 16 + l15];
        }
#pragma unroll
        for (int r = 0; r < 4; r++) {
            int mg = mrow + q * 4 + r;
            float ps = 0.f, pn = 0.f;
#pragma unroll
            for (int t = 0; t < 4; t++) {
                float v = acc[hh][t][r];
                ps += v * asc[t];
                pn += v * anc[t];
                if (mg < N)
                    Cs[(size_t)mg * 128 + t * 16 + l15] = __float2half(v);
            }
#pragma unroll
            for (int m = 8; m >= 1; m >>= 1) {
                ps += __shfl_xor(ps, m, 64);
                pn += __shfl_xor(pn, m, 64);
            }
            if (l15 == 0 && mg < N) {
                g_as1[mg * 8 + h] = ps;
                g_an1[mg * 8 + h] = pn;
            }
        }
    }
}

// ---------------------------------------------------------------------------
// K2: layer-1 aggregation, L2-BLOCKED over head pairs (hp = bid&3 -> slab
// pinned to XCDs {hp, hp+4}; round-3 counter-proven: losing this costs
// FETCH 37->60MB, ~25us). MLP-unrolled: 32 edges/step (four 8-slot groups),
// all 8 half8 + 4 ushort + 4 float loads issued before any dependent use.
// Clamped slots re-read row[deg-1] (same line, cached; e=0 masks).
// ---------------------------------------------------------------------------
__global__ __launch_bounds__(256) void agg_h8_sliced(int N, int slabN) {
    int bid = blockIdx.x;
    int hp = bid & 3;                      // phase = head pair, XCD-interleaved
    int rem = bid >> 2;
    int d = rem * 4 + (threadIdx.x >> 6);
    int lane = threadIdx.x & 63;
    if (d >= N) return;
    const int sub = lane >> 3;             // edge slot 0..7
    const int inner = lane & 7;
    const int hh = inner >> 2;             // head within pair
    const int h = hp * 2 + hh;
    const int c16 = (inner & 3) * 16;      // halves c16..c16+15 of the head

    int deg = g_cnt[d];
    const unsigned short* row = g_ell + (d << 6);
    float asd = g_as1[d * 8 + h];
    const __half* slab = g_proj1p + (size_t)hp * slabN;

    float acc[16];
#pragma unroll
    for (int i = 0; i < 16; i++) acc[i] = 0.f;
    float den = 0.f;
    if (sub == 0) {   // self-loop (s = d)
        float e = __expf(leaky(asd + g_an1[d * 8 + h]));
        const __half* p = slab + (size_t)d * 128 + hh * 64 + c16;
        half8 v0 = *(const half8*)p;
        half8 v1 = *(const half8*)(p + 8);
        den = e;
#pragma unroll
        for (int i = 0; i < 8; i++) {
            acc[i] = e * (float)v0[i];
            acc[8 + i] = e * (float)v1[i];
        }
    }
    for (int j0 = 0; j0 < deg; j0 += 32) {
        int jj[4], sv[4];
        float en[4];
        half8 v0[4], v1[4];
#pragma unroll
        for (int g = 0; g < 4; g++) {
            jj[g] = j0 + g * 8 + sub;
            int jc = (jj[g] < deg) ? jj[g] : (deg - 1);  // deg > 0 here
            sv[g] = row[jc];
        }
#pragma unroll
        for (int g = 0; g < 4; g++) en[g] = g_an1[sv[g] * 8 + h];
#pragma unroll
        for (int g = 0; g < 4; g++) {
            const __half* p = slab + (size_t)sv[g] * 128 + hh * 64 + c16;
            v0[g] = *(const half8*)p;
            v1[g] = *(const half8*)(p + 8);
        }
#pragma unroll
        for (int g = 0; g < 4; g++) {
            float e = __expf(leaky(asd + en[g]));
            if (jj[g] >= deg) e = 0.f;
            den += e;
#pragma unroll
            for (int i = 0; i < 8; i++) {
                acc[i]     += e * (float)v0[g][i];
                acc[8 + i] += e * (float)v1[g][i];
            }
        }
    }

    // combine the 8 edge-slot partials (lane l += l+32, l+16, l+8)
#pragma unroll
    for (int off = 32; off >= 8; off >>= 1) {
#pragma unroll
        for (int i = 0; i < 16; i++) acc[i] += __shfl_down(acc[i], off, 64);
        den += __shfl_down(den, off, 64);
    }

    if (sub == 0) {
        float r = 1.f / den;     // den > 0 (self-loop)
        half8 o0, o1;
#pragma unroll
        for (int i = 0; i < 8; i++) {
            o0[i] = (_Float16)elu1(acc[i] * r);
            o1[i] = (_Float16)elu1(acc[8 + i] * r);
        }
        __half* op = g_hbufh + (size_t)d * 512 + h * 64 + c16;
        *(half8*)op = o0;
        *(half8*)(op + 8) = o1;
    }
}

// ---------------------------------------------------------------------------
// K3: layer-2 GEMM via MFMA, K=512 in registers. ONE WAVE PER BLOCK (64
// thr), 16-row tile -> 625 blocks across all 256 CUs. Epilogue: half proj2h
// store + fused alpha2. (Identical to round-2/4 verified version.)
// ---------------------------------------------------------------------------
__global__ __launch_bounds__(64) void mfma_gemm2(
    const float* __restrict__ a2, int M) {
    const int lane = threadIdx.x & 63;
    const int q = lane >> 4;
    const int l15 = lane & 15;
    const int mrow = blockIdx.x * 16;

    f32x4 acc[4] = {{0.f, 0.f, 0.f, 0.f}, {0.f, 0.f, 0.f, 0.f},
                    {0.f, 0.f, 0.f, 0.f}, {0.f, 0.f, 0.f, 0.f}};
    const __half* Ap = g_hbufh + (size_t)(mrow + l15) * 512 + q * 8;
    const __half* Bp = g_W2t + (size_t)l15 * 512 + q * 8;
#pragma unroll
    for (int ks = 0; ks < 16; ks++) {
        half8 av = *(const half8*)(Ap + ks * 32);
#pragma unroll
        for (int t = 0; t < 4; t++) {
            half8 bv = *(const half8*)(Bp + (size_t)t * 16 * 512 + ks * 32);
            acc[t] = __builtin_amdgcn_mfma_f32_16x16x32_f16(av, bv, acc[t], 0, 0, 0);
        }
    }

    float asc[4], anc[4];
#pragma unroll
    for (int t = 0; t < 4; t++) {
        asc[t] = a2[t * 16 + l15];
        anc[t] = a2[64 + t * 16 + l15];
    }
#pragma unroll
    for (int r = 0; r < 4; r++) {
        int mg = mrow + q * 4 + r;
        float ps = 0.f, pn = 0.f;
#pragma unroll
        for (int t = 0; t < 4; t++) {
            float v = acc[t][r];
            ps += v * asc[t];
            pn += v * anc[t];
            if (mg < M)
                g_proj2h[(size_t)mg * 64 + t * 16 + l15] = __float2half(v);
        }
#pragma unroll
        for (int m = 8; m >= 1; m >>= 1) {
            ps += __shfl_xor(ps, m, 64);
            pn += __shfl_xor(pn, m, 64);
        }
        if (l15 == 0 && mg < M) {
            g_as2[mg] = ps;
            g_an2[mg] = pn;
        }
    }
}

// ---------------------------------------------------------------------------
// K4: layer-2 aggregation (H=1): one wave per node; MLP-unrolled 32
// edges/step (verified round 4). fp16 proj (1.28MB, L2-resident); self-loop
// in writer lanes' epilogue; fp32 out via two float4.
// ALSO resets g_cnt[d]=0 for the next iteration (after reading deg).
// ---------------------------------------------------------------------------
__global__ __launch_bounds__(256) void agg_node_h1(float* __restrict__ out,
                                                   int N) {
    int d = blockIdx.x * 4 + (threadIdx.x >> 6);
    int lane = threadIdx.x & 63;
    if (d >= N) return;
    int sub = lane >> 3;                   // edge slot 0..7
    int inner = lane & 7;                  // 8-half chunk
    int deg = g_cnt[d];
    if (lane == 0) g_cnt[d] = 0;           // self-reset for next iteration
    const unsigned short* row = g_ell + (d << 6);
    float asd = g_as2[d];

    float acc[8];
#pragma unroll
    for (int i = 0; i < 8; i++) acc[i] = 0.f;
    float den = 0.f;
    for (int j0 = 0; j0 < deg; j0 += 32) {
        int jj[4], s[4];
        float en[4];
        half8 v[4];
#pragma unroll
        for (int g = 0; g < 4; g++) {
            jj[g] = j0 + g * 8 + sub;
            int jc = (jj[g] < deg) ? jj[g] : (deg - 1);  // deg > 0 here
            s[g] = row[jc];
        }
#pragma unroll
        for (int g = 0; g < 4; g++) en[g] = g_an2[s[g]];
#pragma unroll
        for (int g = 0; g < 4; g++)
            v[g] = *(const half8*)(g_proj2h + (size_t)s[g] * 64 + inner * 8);
#pragma unroll
        for (int g = 0; g < 4; g++) {
            float e = __expf(leaky(asd + en[g]));
            if (jj[g] >= deg) e = 0.f;
            den += e;
#pragma unroll
            for (int i = 0; i < 8; i++) acc[i] += e * (float)v[g][i];
        }
    }

#pragma unroll
    for (int off = 32; off >= 8; off >>= 1) {
#pragma unroll
        for (int i = 0; i < 8; i++) acc[i] += __shfl_down(acc[i], off, 64);
        den += __shfl_down(den, off, 64);
    }

    if (sub == 0) {
        // self-loop (s = d)
        float e = __expf(leaky(asd + g_an2[d]));
        half8 v = *(const half8*)(g_proj2h + (size_t)d * 64 + inner * 8);
        den += e;
#pragma unroll
        for (int i = 0; i < 8; i++) acc[i] += e * (float)v[i];
        float rden = 1.f / den;
        float4 r0, r1;
        r0.x = acc[0] * rden; r0.y = acc[1] * rden;
        r0.z = acc[2] * rden; r0.w = acc[3] * rden;
        r1.x = acc[4] * rden; r1.y = acc[5] * rden;
        r1.z = acc[6] * rden; r1.w = acc[7] * rden;
        float* op = out + (size_t)d * 64 + inner * 8;
        *(float4*)op = r0;
        *(float4*)(op + 4) = r1;
    }
}

extern "C" void kernel_launch(void* const* d_in, const int* in_sizes, int n_in,
                              void* d_out, int out_size, void* d_ws, size_t ws_size,
                              hipStream_t stream) {
    const float* x  = (const float*)d_in[0];
    const int* edges = (const int*)d_in[1];
    const float* W1 = (const float*)d_in[2];
    const float* a1 = (const float*)d_in[3];
    const float* W2 = (const float*)d_in[4];
    const float* a2 = (const float*)d_in[5];

    const int Din = 128, Dmid = 512;
    const int N = in_sizes[0] / Din;       // 10000
    const int E0 = in_sizes[1] / 2;        // 80000
    const int Mpad = (N + 63) & ~63;       // pad rows for MFMA tiles
    const int slabN = Mpad * 128;          // halves per head-pair slab
    (void)W1; (void)d_ws; (void)ws_size;

    // ---- K1: ELL scatter + W2 transpose + layer-1 MFMA GEMM (hp blocks) ----
    int t2 = Dmid * 64;                    // 32768 W2 elements
    int nscat = (2 * E0 + t2 + 255) / 256;
    int ngemm = 4 * (Mpad / 64);           // head-pair x 64-row tiles
    k1_scatter_gemm1<<<nscat + ngemm, 256, 0, stream>>>(
        edges, E0, W2, t2, nscat, (const float4*)x, W1, a1, N, slabN);

    // ---- K2: L2-blocked softmax-agg + ELU (hp-sliced, 32-edge MLP) ----
    int nbp = (N + 3) / 4;
    agg_h8_sliced<<<4 * nbp, 256, 0, stream>>>(N, slabN);

    // ---- K3: layer-2 MFMA GEMM (one wave/block) + fused alpha2 ----
    mfma_gemm2<<<(N + 15) / 16, 64, 0, stream>>>(a2, N);

    // ---- K4: layer-2 aggregation + g_cnt self-reset ----
    agg_node_h1<<<(N + 3) / 4, 256, 0, stream>>>((float*)d_out, N);
}

// Round 7
// 132.508 us; speedup vs baseline: 9.8621x; 1.0446x over previous
//
#include <hip/hip_runtime.h>
#include <hip/hip_fp16.h>

#define RELU_NEG_SLOPE 0.2f

typedef _Float16 half8 __attribute__((ext_vector_type(8)));
typedef float f32x4 __attribute__((ext_vector_type(4)));

__device__ __forceinline__ float leaky(float e) {
    return (e > 0.f) ? e : RELU_NEG_SLOPE * e;
}

__device__ __forceinline__ float elu1(float x) {
    return (x > 0.f) ? x : (__expf(x) - 1.f);
}

// ---------------------------------------------------------------------------
// All scratch in __device__ globals (zero-init .bss), NOT the poisoned
// workspace (validated rounds 2-4: graph-replay + rocprof safe).
// g_cnt is self-resetting: K4 (last consumer) writes cnt[d]=0 after
// reading. Everything else is fully rewritten before being read.
// N=10000 <= 16384; deg <= 64 (Poisson(16): P(deg>64) ~ 1e-20).
// NOTE (rounds 1+5): cross-XCD visibility primitives (grid.sync, per-block
// __threadfence) cost ~µs each on gfx950 — dispatch boundaries are the
// CHEAP way to get device-wide visibility. Keep 4 dispatches.
// Round-6 counters: agg_h8_sliced ~42us, VALUBusy 58%, HBM 7.6% ->
// VALU/issue-bound; this round dedups its redundant per-lane work.
// ---------------------------------------------------------------------------
#define MAXN 16384
#define MAXPAD 16384

__device__ __align__(256) int            g_cnt[MAXN];
__device__ __align__(256) unsigned short g_ell[MAXN * 64];
__device__ __align__(256) __half         g_proj1p[(size_t)4 * MAXPAD * 128];
__device__ __align__(256) __half         g_hbufh[(size_t)MAXPAD * 512];
__device__ __align__(256) __half         g_W2t[64 * 512];
__device__ __align__(256) __half         g_proj2h[MAXN * 64];
__device__ __align__(256) float          g_as1[MAXN * 8];
__device__ __align__(256) float          g_an1[MAXN * 8];
__device__ __align__(256) float          g_as2[MAXN];
__device__ __align__(256) float          g_an2[MAXN];

// ---------------------------------------------------------------------------
// K1: fused ELL scatter + W2 transpose (blocks [0,nscat)) + layer-1 MFMA
// GEMM (the rest). EXACT round-4 version (131.5us best base):
//   - A: direct fp32 float4 loads from x + in-register RTN fp16 convert.
//   - B: per-block LDS transpose of W1[h] (32KB coalesced read -> fp16 B^T
//     tile, row stride 132 halves).
// C written PERMUTED into 4 head-pair slabs (each 2.57 MB -> fits one XCD
// L2): g_proj1p[(h>>1)*slabN + n*128 + (h&1)*64 + f], slabN = Mpad*128.
// ---------------------------------------------------------------------------
__global__ __launch_bounds__(256) void k1_scatter_gemm1(
    const int* __restrict__ edges, int E0,
    const float* __restrict__ W2, int t2, int nscat,
    const float4* __restrict__ x4, const float* __restrict__ W1,
    const float* __restrict__ a1, int N, int slabN) {
    __shared__ __half Bs[64 * 132];        // B^T tile, padded stride
    if (blockIdx.x < nscat) {
        int i = blockIdx.x * 256 + threadIdx.x;
        if (i < 2 * E0) {
            int s = edges[i];
            int d = (i < E0) ? edges[E0 + i] : edges[i - E0];
            int pos = atomicAdd(&g_cnt[d], 1);
            g_ell[(d << 6) + pos] = (unsigned short)s;
        } else if (i < 2 * E0 + t2) {
            int j = i - 2 * E0;
            int f = j & 63;
            int d = j >> 6;
            g_W2t[f * 512 + d] = __float2half(W2[j]);
        }
        return;
    }
    int bid2 = blockIdx.x - nscat;
    const int h = bid2 & 7;
    const int by = bid2 >> 3;

    // stage W1[h] (128x64 fp32, f-contiguous) -> Bs[f*132 + d] fp16
    {
        const float4* W1h = (const float4*)W1 + h * 2048;
        int t = threadIdx.x;
#pragma unroll
        for (int r = 0; r < 8; r++) {
            int j4 = t + r * 256;          // float4 index: 4 consecutive f
            float4 w = W1h[j4];
            int f = (j4 << 2) & 63;
            int d = j4 >> 4;
            Bs[(f + 0) * 132 + d] = __float2half(w.x);
            Bs[(f + 1) * 132 + d] = __float2half(w.y);
            Bs[(f + 2) * 132 + d] = __float2half(w.z);
            Bs[(f + 3) * 132 + d] = __float2half(w.w);
        }
    }
    __syncthreads();

    const int lane = threadIdx.x & 63;
    const int wave = threadIdx.x >> 6;
    const int q = lane >> 4;
    const int l15 = lane & 15;
    const int mrow = by * 64 + wave * 16;

    int arow = mrow + l15;
    if (arow >= N) arow = N - 1;           // pad rows: clamp (values unused)
    const float4* Ar = x4 + (size_t)arow * 32;

    f32x4 acc[4] = {{0.f, 0.f, 0.f, 0.f}, {0.f, 0.f, 0.f, 0.f},
                    {0.f, 0.f, 0.f, 0.f}, {0.f, 0.f, 0.f, 0.f}};
#pragma unroll
    for (int ks = 0; ks < 4; ks++) {
        float4 a0 = Ar[ks * 8 + q * 2];
        float4 a1v = Ar[ks * 8 + q * 2 + 1];
        half8 av;
        av[0] = (_Float16)a0.x; av[1] = (_Float16)a0.y;
        av[2] = (_Float16)a0.z; av[3] = (_Float16)a0.w;
        av[4] = (_Float16)a1v.x; av[5] = (_Float16)a1v.y;
        av[6] = (_Float16)a1v.z; av[7] = (_Float16)a1v.w;
#pragma unroll
        for (int t = 0; t < 4; t++) {
            half8 bv = *(const half8*)(Bs + (t * 16 + l15) * 132 + q * 8 + ks * 32);
            acc[t] = __builtin_amdgcn_mfma_f32_16x16x32_f16(av, bv, acc[t], 0, 0, 0);
        }
    }

    __half* Cs = g_proj1p + (size_t)(h >> 1) * slabN + (h & 1) * 64;
    float asc[4], anc[4];
#pragma unroll
    for (int t = 0; t < 4; t++) {
        asc[t] = a1[h * 128 + t * 16 + l15];
        anc[t] = a1[h * 128 + 64 + t * 16 + l15];
    }
#pragma unroll
    for (int r = 0; r < 4; r++) {
        int mg = mrow + q * 4 + r;
        float ps = 0.f, pn = 0.f;
#pragma unroll
        for (int t = 0; t < 4; t++) {
            float v = acc[t][r];
            ps += v * asc[t];
            pn += v * anc[t];
            if (mg < N)
                Cs[(size_t)mg * 128 + t * 16 + l15] = __float2half(v);
        }
#pragma unroll
        for (int m = 8; m >= 1; m >>= 1) {
            ps += __shfl_xor(ps, m, 64);
            pn += __shfl_xor(pn, m, 64);
        }
        if (l15 == 0 && mg < N) {
            g_as1[mg * 8 + h] = ps;
            g_an1[mg * 8 + h] = pn;
        }
    }
}

// ---------------------------------------------------------------------------
// K2: layer-1 aggregation, L2-BLOCKED over head pairs (hp = bid&3; round-3
// counter-proven: losing this costs FETCH 37->60MB, ~25us).
// ROUND-7: producer/consumer dedup + 32-bit offset addressing.
//   Old: every lane loaded 2 idx + 2 an1 + ran 2 exp chains per 16-edge
//   step (8x duplicated across the edge-slot group) with 64-bit addr math.
//   New: lane L (mod 32) is PRODUCER for (edge j0+(L&15), head (L>>4)&1):
//   1 idx load + 1 an1 load + 1 exp, mask folded in. Consumers pull s/e via
//   4 ds_bpermute (addresses hoisted). Gathers: uniform slab base + 32-bit
//   voffset (s<<8 + const), second half8 at +16 immediate.
// Numerics identical to round 4 (same e values, same accumulation order).
// ---------------------------------------------------------------------------
__global__ __launch_bounds__(256) void agg_h8_sliced(int N, int slabN) {
    int bid = blockIdx.x;
    int hp = bid & 3;                      // phase = head pair, XCD-interleaved
    int rem = bid >> 2;
    int d = rem * 4 + (threadIdx.x >> 6);
    int lane = threadIdx.x & 63;
    if (d >= N) return;
    const int sub = lane >> 3;             // edge slot 0..7
    const int inner = lane & 7;
    const int hh = inner >> 2;             // head within pair
    const int h = hp * 2 + hh;
    const int c16 = (inner & 3) * 16;      // halves c16..c16+15 of the head

    int deg = g_cnt[d];
    const unsigned short* row = g_ell + (d << 6);
    float asd = g_as1[d * 8 + h];
    const char* slabB = (const char*)g_proj1p + (size_t)hp * slabN * 2;
    const unsigned rowoff = (unsigned)((hh * 64 + c16) * 2);  // byte sub-off

    // producer identity (lanes 32-63 mirror 0-31; harmless duplication)
    const int pedge = lane & 15;
    const int phead = (lane >> 4) & 1;
    float pasd = g_as1[d * 8 + hp * 2 + phead];
    // hoisted shuffle source lanes
    const int la_s = sub;                  // s for edge j0+sub
    const int lb_s = sub + 8;              // s for edge j0+sub+8
    const int la_e = sub + (hh << 4);      // e for (edge j0+sub, head hh)
    const int lb_e = sub + 8 + (hh << 4);

    float acc[16];
#pragma unroll
    for (int i = 0; i < 16; i++) acc[i] = 0.f;
    float den = 0.f;
    if (sub == 0) {   // self-loop (s = d)
        float e = __expf(leaky(asd + g_an1[d * 8 + h]));
        const char* p = slabB + ((unsigned)d << 8) + rowoff;
        half8 v0 = *(const half8*)p;
        half8 v1 = *(const half8*)(p + 16);
        den = e;
#pragma unroll
        for (int i = 0; i < 8; i++) {
            acc[i] = e * (float)v0[i];
            acc[8 + i] = e * (float)v1[i];
        }
    }
    for (int j0 = 0; j0 < deg; j0 += 16) {
        // producer: one edge x one head per lane (deg > 0 inside this loop)
        int j = j0 + pedge;
        int jc = (j < deg) ? j : (deg - 1);
        int sp = row[jc];
        float an = g_an1[sp * 8 + hp * 2 + phead];
        float ev = __expf(leaky(pasd + an));
        if (j >= deg) ev = 0.f;
        // consumers: pull s and e for this lane's two edge slots
        int sa = __shfl(sp, la_s, 64);
        int sb = __shfl(sp, lb_s, 64);
        float ea = __shfl(ev, la_e, 64);
        float eb = __shfl(ev, lb_e, 64);
        unsigned offa = ((unsigned)sa << 8) + rowoff;
        unsigned offb = ((unsigned)sb << 8) + rowoff;
        half8 va0 = *(const half8*)(slabB + offa);
        half8 va1 = *(const half8*)(slabB + offa + 16);
        half8 vb0 = *(const half8*)(slabB + offb);
        half8 vb1 = *(const half8*)(slabB + offb + 16);
        den += ea + eb;
#pragma unroll
        for (int i = 0; i < 8; i++) {
            acc[i]     += ea * (float)va0[i] + eb * (float)vb0[i];
            acc[8 + i] += ea * (float)va1[i] + eb * (float)vb1[i];
        }
    }

    // combine the 8 edge-slot partials (lane l += l+32, l+16, l+8)
#pragma unroll
    for (int off = 32; off >= 8; off >>= 1) {
#pragma unroll
        for (int i = 0; i < 16; i++) acc[i] += __shfl_down(acc[i], off, 64);
        den += __shfl_down(den, off, 64);
    }

    if (sub == 0) {
        float r = 1.f / den;     // den > 0 (self-loop)
        half8 o0, o1;
#pragma unroll
        for (int i = 0; i < 8; i++) {
            o0[i] = (_Float16)elu1(acc[i] * r);
            o1[i] = (_Float16)elu1(acc[8 + i] * r);
        }
        __half* op = g_hbufh + (size_t)d * 512 + h * 64 + c16;
        *(half8*)op = o0;
        *(half8*)(op + 8) = o1;
    }
}

// ---------------------------------------------------------------------------
// K3: layer-2 GEMM via MFMA, K=512 in registers. ONE WAVE PER BLOCK (64
// thr), 16-row tile -> 625 blocks across all 256 CUs. Epilogue: half proj2h
// store + fused alpha2. (Identical to round-2/4 verified version.)
// ---------------------------------------------------------------------------
__global__ __launch_bounds__(64) void mfma_gemm2(
    const float* __restrict__ a2, int M) {
    const int lane = threadIdx.x & 63;
    const int q = lane >> 4;
    const int l15 = lane & 15;
    const int mrow = blockIdx.x * 16;

    f32x4 acc[4] = {{0.f, 0.f, 0.f, 0.f}, {0.f, 0.f, 0.f, 0.f},
                    {0.f, 0.f, 0.f, 0.f}, {0.f, 0.f, 0.f, 0.f}};
    const __half* Ap = g_hbufh + (size_t)(mrow + l15) * 512 + q * 8;
    const __half* Bp = g_W2t + (size_t)l15 * 512 + q * 8;
#pragma unroll
    for (int ks = 0; ks < 16; ks++) {
        half8 av = *(const half8*)(Ap + ks * 32);
#pragma unroll
        for (int t = 0; t < 4; t++) {
            half8 bv = *(const half8*)(Bp + (size_t)t * 16 * 512 + ks * 32);
            acc[t] = __builtin_amdgcn_mfma_f32_16x16x32_f16(av, bv, acc[t], 0, 0, 0);
        }
    }

    float asc[4], anc[4];
#pragma unroll
    for (int t = 0; t < 4; t++) {
        asc[t] = a2[t * 16 + l15];
        anc[t] = a2[64 + t * 16 + l15];
    }
#pragma unroll
    for (int r = 0; r < 4; r++) {
        int mg = mrow + q * 4 + r;
        float ps = 0.f, pn = 0.f;
#pragma unroll
        for (int t = 0; t < 4; t++) {
            float v = acc[t][r];
            ps += v * asc[t];
            pn += v * anc[t];
            if (mg < M)
                g_proj2h[(size_t)mg * 64 + t * 16 + l15] = __float2half(v);
        }
#pragma unroll
        for (int m = 8; m >= 1; m >>= 1) {
            ps += __shfl_xor(ps, m, 64);
            pn += __shfl_xor(pn, m, 64);
        }
        if (l15 == 0 && mg < M) {
            g_as2[mg] = ps;
            g_an2[mg] = pn;
        }
    }
}

// ---------------------------------------------------------------------------
// K4: layer-2 aggregation (H=1): one wave per node; ROUND-7 producer/
// consumer dedup: lane L (mod 32) produces e for edge j0+(L&31) (1 idx +
// 1 an2 load + 1 exp, mask folded); consumers pull s/e via 8 ds_bpermute.
// 32-bit offset gathers (proj2h row = 128 B). Self-loop in writer lanes'
// epilogue; fp32 out via two float4. ALSO resets g_cnt[d]=0.
// ---------------------------------------------------------------------------
__global__ __launch_bounds__(256) void agg_node_h1(float* __restrict__ out,
                                                   int N) {
    int d = blockIdx.x * 4 + (threadIdx.x >> 6);
    int lane = threadIdx.x & 63;
    if (d >= N) return;
    int sub = lane >> 3;                   // edge slot 0..7
    int inner = lane & 7;                  // 8-half chunk
    int deg = g_cnt[d];
    if (lane == 0) g_cnt[d] = 0;           // self-reset for next iteration
    const unsigned short* row = g_ell + (d << 6);
    float asd = g_as2[d];
    const char* projB = (const char*)g_proj2h;
    const unsigned rowoff = (unsigned)(inner * 16);  // byte sub-offset

    const int pedge = lane & 31;           // producer edge (mirrored 32-63)

    float acc[8];
#pragma unroll
    for (int i = 0; i < 8; i++) acc[i] = 0.f;
    float den = 0.f;
    for (int j0 = 0; j0 < deg; j0 += 32) {
        int j = j0 + pedge;
        int jc = (j < deg) ? j : (deg - 1);   // deg > 0 inside this loop
        int sp = row[jc];
        float ev = __expf(leaky(asd + g_an2[sp]));
        if (j >= deg) ev = 0.f;
#pragma unroll
        for (int g = 0; g < 4; g++) {
            int src = g * 8 + sub;
            int s = __shfl(sp, src, 64);
            float e = __shfl(ev, src, 64);
            unsigned off = ((unsigned)s << 7) + rowoff;
            half8 v = *(const half8*)(projB + off);
            den += e;
#pragma unroll
            for (int i = 0; i < 8; i++) acc[i] += e * (float)v[i];
        }
    }

#pragma unroll
    for (int off = 32; off >= 8; off >>= 1) {
#pragma unroll
        for (int i = 0; i < 8; i++) acc[i] += __shfl_down(acc[i], off, 64);
        den += __shfl_down(den, off, 64);
    }

    if (sub == 0) {
        // self-loop (s = d)
        float e = __expf(leaky(asd + g_an2[d]));
        half8 v = *(const half8*)(projB + ((unsigned)d << 7) + rowoff);
        den += e;
#pragma unroll
        for (int i = 0; i < 8; i++) acc[i] += e * (float)v[i];
        float rden = 1.f / den;
        float4 r0, r1;
        r0.x = acc[0] * rden; r0.y = acc[1] * rden;
        r0.z = acc[2] * rden; r0.w = acc[3] * rden;
        r1.x = acc[4] * rden; r1.y = acc[5] * rden;
        r1.z = acc[6] * rden; r1.w = acc[7] * rden;
        float* op = out + (size_t)d * 64 + inner * 8;
        *(float4*)op = r0;
        *(float4*)(op + 4) = r1;
    }
}

extern "C" void kernel_launch(void* const* d_in, const int* in_sizes, int n_in,
                              void* d_out, int out_size, void* d_ws, size_t ws_size,
                              hipStream_t stream) {
    const float* x  = (const float*)d_in[0];
    const int* edges = (const int*)d_in[1];
    const float* W1 = (const float*)d_in[2];
    const float* a1 = (const float*)d_in[3];
    const float* W2 = (const float*)d_in[4];
    const float* a2 = (const float*)d_in[5];

    const int Din = 128, H1 = 8, Dmid = 512;
    const int N = in_sizes[0] / Din;       // 10000
    const int E0 = in_sizes[1] / 2;        // 80000
    const int Mpad = (N + 63) & ~63;       // pad rows for MFMA tiles
    const int slabN = Mpad * 128;          // halves per head-pair slab
    (void)d_ws; (void)ws_size;

    // ---- K1: ELL scatter + W2 transpose + layer-1 MFMA GEMM ----
    int t2 = Dmid * 64;                    // 32768 W2 elements
    int nscat = (2 * E0 + t2 + 255) / 256;
    int ngemm = H1 * (Mpad / 64);
    k1_scatter_gemm1<<<nscat + ngemm, 256, 0, stream>>>(
        edges, E0, W2, t2, nscat, (const float4*)x, W1, a1, N, slabN);

    // ---- K2: L2-blocked softmax-agg + ELU (hp-sliced, dedup'd) ----
    int nbp = (N + 3) / 4;
    agg_h8_sliced<<<4 * nbp, 256, 0, stream>>>(N, slabN);

    // ---- K3: layer-2 MFMA GEMM (one wave/block) + fused alpha2 ----
    mfma_gemm2<<<(N + 15) / 16, 64, 0, stream>>>(a2, N);

    // ---- K4: layer-2 aggregation + g_cnt self-reset ----
    agg_node_h1<<<(N + 3) / 4, 256, 0, stream>>>((float*)d_out, N);
}

// Round 8
// 124.696 us; speedup vs baseline: 10.4799x; 1.0626x over previous
//
#include <hip/hip_runtime.h>
#include <hip/hip_fp16.h>

#define RELU_NEG_SLOPE 0.2f

typedef _Float16 half8 __attribute__((ext_vector_type(8)));
typedef float f32x4 __attribute__((ext_vector_type(4)));

__device__ __forceinline__ float leaky(float e) {
    return (e > 0.f) ? e : RELU_NEG_SLOPE * e;
}

__device__ __forceinline__ float elu1(float x) {
    return (x > 0.f) ? x : (__expf(x) - 1.f);
}

// ---------------------------------------------------------------------------
// All scratch in __device__ globals (zero-init .bss), NOT the poisoned
// workspace (validated rounds 2-7: graph-replay + rocprof safe).
// g_cnt is self-resetting: K4 (last consumer) writes cnt[d]=0 after reading.
// N=10000 <= 16384; deg <= 64 (Poisson(16): P(deg>64) ~ 1e-20).
// NOTES:
//  - rounds 1+5: cross-XCD visibility primitives (grid.sync, per-block
//    threadfence) cost ~µs each on gfx950 — dispatch boundaries are the
//    cheap way to get device-wide visibility. Keep 4 dispatches.
//  - round 3: hp-slab L2 blocking is worth ~25us (FETCH 37->60MB without).
//  - round 7: dedup pays only if it doesn't lengthen the dependent chain
//    (K4's serialized producer regressed; reverted here).
//  - round 8: K2 lane remap 8x8 -> 4x16: slot-reduce 102->18 ops, epilogue
//    100->~50, full-row-per-edge coalescing (8 lines/load-instr).
// ---------------------------------------------------------------------------
#define MAXN 16384
#define MAXPAD 16384

__device__ __align__(256) int            g_cnt[MAXN];
__device__ __align__(256) unsigned short g_ell[MAXN * 64];
__device__ __align__(256) __half         g_proj1p[(size_t)4 * MAXPAD * 128];
__device__ __align__(256) __half         g_hbufh[(size_t)MAXPAD * 512];
__device__ __align__(256) __half         g_W2t[64 * 512];
__device__ __align__(256) __half         g_proj2h[MAXN * 64];
__device__ __align__(256) float          g_as1[MAXN * 8];
__device__ __align__(256) float          g_an1[MAXN * 8];
__device__ __align__(256) float          g_as2[MAXN];
__device__ __align__(256) float          g_an2[MAXN];

// ---------------------------------------------------------------------------
// K1: fused ELL scatter + W2 transpose (blocks [0,nscat)) + layer-1 MFMA
// GEMM (the rest). EXACT round-4 version:
//   - A: direct fp32 float4 loads from x + in-register RTN fp16 convert.
//   - B: per-block LDS transpose of W1[h] (32KB coalesced -> fp16 B^T tile,
//     row stride 132 halves).
// C written PERMUTED into 4 head-pair slabs (each 2.57 MB -> fits one XCD
// L2): g_proj1p[(h>>1)*slabN + n*128 + (h&1)*64 + f], slabN = Mpad*128.
// ---------------------------------------------------------------------------
__global__ __launch_bounds__(256) void k1_scatter_gemm1(
    const int* __restrict__ edges, int E0,
    const float* __restrict__ W2, int t2, int nscat,
    const float4* __restrict__ x4, const float* __restrict__ W1,
    const float* __restrict__ a1, int N, int slabN) {
    __shared__ __half Bs[64 * 132];        // B^T tile, padded stride
    if (blockIdx.x < nscat) {
        int i = blockIdx.x * 256 + threadIdx.x;
        if (i < 2 * E0) {
            int s = edges[i];
            int d = (i < E0) ? edges[E0 + i] : edges[i - E0];
            int pos = atomicAdd(&g_cnt[d], 1);
            g_ell[(d << 6) + pos] = (unsigned short)s;
        } else if (i < 2 * E0 + t2) {
            int j = i - 2 * E0;
            int f = j & 63;
            int d = j >> 6;
            g_W2t[f * 512 + d] = __float2half(W2[j]);
        }
        return;
    }
    int bid2 = blockIdx.x - nscat;
    const int h = bid2 & 7;
    const int by = bid2 >> 3;

    // stage W1[h] (128x64 fp32, f-contiguous) -> Bs[f*132 + d] fp16
    {
        const float4* W1h = (const float4*)W1 + h * 2048;
        int t = threadIdx.x;
#pragma unroll
        for (int r = 0; r < 8; r++) {
            int j4 = t + r * 256;          // float4 index: 4 consecutive f
            float4 w = W1h[j4];
            int f = (j4 << 2) & 63;
            int d = j4 >> 4;
            Bs[(f + 0) * 132 + d] = __float2half(w.x);
            Bs[(f + 1) * 132 + d] = __float2half(w.y);
            Bs[(f + 2) * 132 + d] = __float2half(w.z);
            Bs[(f + 3) * 132 + d] = __float2half(w.w);
        }
    }
    __syncthreads();

    const int lane = threadIdx.x & 63;
    const int wave = threadIdx.x >> 6;
    const int q = lane >> 4;
    const int l15 = lane & 15;
    const int mrow = by * 64 + wave * 16;

    int arow = mrow + l15;
    if (arow >= N) arow = N - 1;           // pad rows: clamp (values unused)
    const float4* Ar = x4 + (size_t)arow * 32;

    f32x4 acc[4] = {{0.f, 0.f, 0.f, 0.f}, {0.f, 0.f, 0.f, 0.f},
                    {0.f, 0.f, 0.f, 0.f}, {0.f, 0.f, 0.f, 0.f}};
#pragma unroll
    for (int ks = 0; ks < 4; ks++) {
        float4 a0 = Ar[ks * 8 + q * 2];
        float4 a1v = Ar[ks * 8 + q * 2 + 1];
        half8 av;
        av[0] = (_Float16)a0.x; av[1] = (_Float16)a0.y;
        av[2] = (_Float16)a0.z; av[3] = (_Float16)a0.w;
        av[4] = (_Float16)a1v.x; av[5] = (_Float16)a1v.y;
        av[6] = (_Float16)a1v.z; av[7] = (_Float16)a1v.w;
#pragma unroll
        for (int t = 0; t < 4; t++) {
            half8 bv = *(const half8*)(Bs + (t * 16 + l15) * 132 + q * 8 + ks * 32);
            acc[t] = __builtin_amdgcn_mfma_f32_16x16x32_f16(av, bv, acc[t], 0, 0, 0);
        }
    }

    __half* Cs = g_proj1p + (size_t)(h >> 1) * slabN + (h & 1) * 64;
    float asc[4], anc[4];
#pragma unroll
    for (int t = 0; t < 4; t++) {
        asc[t] = a1[h * 128 + t * 16 + l15];
        anc[t] = a1[h * 128 + 64 + t * 16 + l15];
    }
#pragma unroll
    for (int r = 0; r < 4; r++) {
        int mg = mrow + q * 4 + r;
        float ps = 0.f, pn = 0.f;
#pragma unroll
        for (int t = 0; t < 4; t++) {
            float v = acc[t][r];
            ps += v * asc[t];
            pn += v * anc[t];
            if (mg < N)
                Cs[(size_t)mg * 128 + t * 16 + l15] = __float2half(v);
        }
#pragma unroll
        for (int m = 8; m >= 1; m >>= 1) {
            ps += __shfl_xor(ps, m, 64);
            pn += __shfl_xor(pn, m, 64);
        }
        if (l15 == 0 && mg < N) {
            g_as1[mg * 8 + h] = ps;
            g_an1[mg * 8 + h] = pn;
        }
    }
}

// ---------------------------------------------------------------------------
// K2: layer-1 aggregation, L2-BLOCKED over head pairs (hp = bid&3).
// ROUND-8 lane remap: 4 edge slots x 16 inner lanes.
//   inner = lane&15 covers 8 halves (16 B) of one head: hh = inner>>3,
//   chunk c8 = inner&7. Each lane processes 2 edges/step (slots sub and
//   sub+4 -> 2 independent 16B gathers in flight), acc[8] fp32.
//   Slot-reduce: 2 rounds (off 32,16) x 9 values = 18 ops (was 3x17=102).
//   Epilogue: 16 active lanes x 8 ELUs (was 8 x 16).
//   Producer dedup (chain-neutral): lanes 0-15 canonical producers
//   (pedge = lane&7, phead = bit3): 1 idx + 1 an1 + 1 exp per 8-edge step;
//   consumers pull s/e via 4 shuffles. 32-bit voffset gathers.
// Numerics: same e values, same per-feature sums; only partial-sum
// association order changes (positive fp32 adds).
// ---------------------------------------------------------------------------
__global__ __launch_bounds__(256) void agg_h8_sliced(int N, int slabN) {
    int bid = blockIdx.x;
    int hp = bid & 3;                      // phase = head pair, XCD-interleaved
    int rem = bid >> 2;
    int d = rem * 4 + (threadIdx.x >> 6);
    int lane = threadIdx.x & 63;
    if (d >= N) return;
    const int sub = lane >> 4;             // edge slot 0..3
    const int inner = lane & 15;
    const int hh = inner >> 3;             // head within pair
    const int h = hp * 2 + hh;
    const int c8 = inner & 7;              // 8-half chunk within the head

    int deg = g_cnt[d];
    const unsigned short* row = g_ell + (d << 6);
    float asd = g_as1[d * 8 + h];
    const char* slabB = (const char*)g_proj1p + (size_t)hp * slabN * 2;
    const unsigned rowoff = (unsigned)(hh * 128 + c8 * 16);  // byte sub-off

    // producer identity (lanes 16+ mirror 0-15; harmless duplication)
    const int pedge = lane & 7;
    const int phead = (lane >> 3) & 1;
    float pasd = g_as1[d * 8 + hp * 2 + phead];
    // hoisted shuffle source lanes
    const int src_sa = sub;                // s for edge j0+sub
    const int src_sb = sub + 4;            // s for edge j0+sub+4
    const int src_ea = sub + (hh << 3);    // e for (edge j0+sub, head hh)
    const int src_eb = sub + 4 + (hh << 3);

    float acc[8];
#pragma unroll
    for (int i = 0; i < 8; i++) acc[i] = 0.f;
    float den = 0.f;
    if (sub == 0) {   // self-loop (s = d), lanes 0-15 cover the full row
        float e = __expf(leaky(asd + g_an1[d * 8 + h]));
        const char* p = slabB + ((unsigned)d << 8) + rowoff;
        half8 v = *(const half8*)p;
        den = e;
#pragma unroll
        for (int i = 0; i < 8; i++) acc[i] = e * (float)v[i];
    }
    for (int j0 = 0; j0 < deg; j0 += 8) {
        // producer: one edge x one head per lane (deg > 0 inside this loop)
        int j = j0 + pedge;
        int jc = (j < deg) ? j : (deg - 1);
        int sp = row[jc];
        float an = g_an1[sp * 8 + hp * 2 + phead];
        float ev = __expf(leaky(pasd + an));
        if (j >= deg) ev = 0.f;
        // consumers: s and e for this lane's two edge slots
        int sa = __shfl(sp, src_sa, 64);
        int sb = __shfl(sp, src_sb, 64);
        float ea = __shfl(ev, src_ea, 64);
        float eb = __shfl(ev, src_eb, 64);
        unsigned offa = ((unsigned)sa << 8) + rowoff;
        unsigned offb = ((unsigned)sb << 8) + rowoff;
        half8 va = *(const half8*)(slabB + offa);
        half8 vb = *(const half8*)(slabB + offb);
        den += ea + eb;
#pragma unroll
        for (int i = 0; i < 8; i++)
            acc[i] += ea * (float)va[i] + eb * (float)vb[i];
    }

    // combine the 4 edge-slot partials (lane l += l+32, l+16)
#pragma unroll
    for (int off = 32; off >= 16; off >>= 1) {
#pragma unroll
        for (int i = 0; i < 8; i++) acc[i] += __shfl_down(acc[i], off, 64);
        den += __shfl_down(den, off, 64);
    }

    if (sub == 0) {
        float r = 1.f / den;     // den > 0 (self-loop)
        half8 o;
#pragma unroll
        for (int i = 0; i < 8; i++) o[i] = (_Float16)elu1(acc[i] * r);
        __half* op = g_hbufh + (size_t)d * 512 + h * 64 + c8 * 8;
        *(half8*)op = o;
    }
}

// ---------------------------------------------------------------------------
// K3: layer-2 GEMM via MFMA, K=512 in registers. ONE WAVE PER BLOCK (64
// thr), 16-row tile -> 625 blocks across all 256 CUs. Epilogue: half proj2h
// store + fused alpha2. (Identical to round-2/4 verified version.)
// ---------------------------------------------------------------------------
__global__ __launch_bounds__(64) void mfma_gemm2(
    const float* __restrict__ a2, int M) {
    const int lane = threadIdx.x & 63;
    const int q = lane >> 4;
    const int l15 = lane & 15;
    const int mrow = blockIdx.x * 16;

    f32x4 acc[4] = {{0.f, 0.f, 0.f, 0.f}, {0.f, 0.f, 0.f, 0.f},
                    {0.f, 0.f, 0.f, 0.f}, {0.f, 0.f, 0.f, 0.f}};
    const __half* Ap = g_hbufh + (size_t)(mrow + l15) * 512 + q * 8;
    const __half* Bp = g_W2t + (size_t)l15 * 512 + q * 8;
#pragma unroll
    for (int ks = 0; ks < 16; ks++) {
        half8 av = *(const half8*)(Ap + ks * 32);
#pragma unroll
        for (int t = 0; t < 4; t++) {
            half8 bv = *(const half8*)(Bp + (size_t)t * 16 * 512 + ks * 32);
            acc[t] = __builtin_amdgcn_mfma_f32_16x16x32_f16(av, bv, acc[t], 0, 0, 0);
        }
    }

    float asc[4], anc[4];
#pragma unroll
    for (int t = 0; t < 4; t++) {
        asc[t] = a2[t * 16 + l15];
        anc[t] = a2[64 + t * 16 + l15];
    }
#pragma unroll
    for (int r = 0; r < 4; r++) {
        int mg = mrow + q * 4 + r;
        float ps = 0.f, pn = 0.f;
#pragma unroll
        for (int t = 0; t < 4; t++) {
            float v = acc[t][r];
            ps += v * asc[t];
            pn += v * anc[t];
            if (mg < M)
                g_proj2h[(size_t)mg * 64 + t * 16 + l15] = __float2half(v);
        }
#pragma unroll
        for (int m = 8; m >= 1; m >>= 1) {
            ps += __shfl_xor(ps, m, 64);
            pn += __shfl_xor(pn, m, 64);
        }
        if (l15 == 0 && mg < M) {
            g_as2[mg] = ps;
            g_an2[mg] = pn;
        }
    }
}

// ---------------------------------------------------------------------------
// K4: layer-2 aggregation (H=1) — EXACT round-4 version (round-7 dedup
// serialized its single-step common case and regressed; reverted).
// One wave per node; 32 edges/step (four independent 8-slot groups).
// fp16 proj (1.28MB, L2-resident); self-loop in writer lanes' epilogue;
// fp32 out via two float4. ALSO resets g_cnt[d]=0 (after reading deg).
// ---------------------------------------------------------------------------
__global__ __launch_bounds__(256) void agg_node_h1(float* __restrict__ out,
                                                   int N) {
    int d = blockIdx.x * 4 + (threadIdx.x >> 6);
    int lane = threadIdx.x & 63;
    if (d >= N) return;
    int sub = lane >> 3;                   // edge slot 0..7
    int inner = lane & 7;                  // 8-half chunk
    int deg = g_cnt[d];
    if (lane == 0) g_cnt[d] = 0;           // self-reset for next iteration
    const unsigned short* row = g_ell + (d << 6);
    float asd = g_as2[d];

    float acc[8];
#pragma unroll
    for (int i = 0; i < 8; i++) acc[i] = 0.f;
    float den = 0.f;
    for (int j0 = 0; j0 < deg; j0 += 32) {
        int jj[4], s[4];
        float en[4];
        half8 v[4];
#pragma unroll
        for (int g = 0; g < 4; g++) {
            jj[g] = j0 + g * 8 + sub;
            int jc = (jj[g] < deg) ? jj[g] : (deg - 1);  // deg > 0 here
            s[g] = row[jc];
        }
#pragma unroll
        for (int g = 0; g < 4; g++) en[g] = g_an2[s[g]];
#pragma unroll
        for (int g = 0; g < 4; g++)
            v[g] = *(const half8*)(g_proj2h + (size_t)s[g] * 64 + inner * 8);
#pragma unroll
        for (int g = 0; g < 4; g++) {
            float e = __expf(leaky(asd + en[g]));
            if (jj[g] >= deg) e = 0.f;
            den += e;
#pragma unroll
            for (int i = 0; i < 8; i++) acc[i] += e * (float)v[g][i];
        }
    }

#pragma unroll
    for (int off = 32; off >= 8; off >>= 1) {
#pragma unroll
        for (int i = 0; i < 8; i++) acc[i] += __shfl_down(acc[i], off, 64);
        den += __shfl_down(den, off, 64);
    }

    if (sub == 0) {
        // self-loop (s = d)
        float e = __expf(leaky(asd + g_an2[d]));
        half8 v = *(const half8*)(g_proj2h + (size_t)d * 64 + inner * 8);
        den += e;
#pragma unroll
        for (int i = 0; i < 8; i++) acc[i] += e * (float)v[i];
        float rden = 1.f / den;
        float4 r0, r1;
        r0.x = acc[0] * rden; r0.y = acc[1] * rden;
        r0.z = acc[2] * rden; r0.w = acc[3] * rden;
        r1.x = acc[4] * rden; r1.y = acc[5] * rden;
        r1.z = acc[6] * rden; r1.w = acc[7] * rden;
        float* op = out + (size_t)d * 64 + inner * 8;
        *(float4*)op = r0;
        *(float4*)(op + 4) = r1;
    }
}

extern "C" void kernel_launch(void* const* d_in, const int* in_sizes, int n_in,
                              void* d_out, int out_size, void* d_ws, size_t ws_size,
                              hipStream_t stream) {
    const float* x  = (const float*)d_in[0];
    const int* edges = (const int*)d_in[1];
    const float* W1 = (const float*)d_in[2];
    const float* a1 = (const float*)d_in[3];
    const float* W2 = (const float*)d_in[4];
    const float* a2 = (const float*)d_in[5];

    const int Din = 128, H1 = 8, Dmid = 512;
    const int N = in_sizes[0] / Din;       // 10000
    const int E0 = in_sizes[1] / 2;        // 80000
    const int Mpad = (N + 63) & ~63;       // pad rows for MFMA tiles
    const int slabN = Mpad * 128;          // halves per head-pair slab
    (void)d_ws; (void)ws_size;

    // ---- K1: ELL scatter + W2 transpose + layer-1 MFMA GEMM ----
    int t2 = Dmid * 64;                    // 32768 W2 elements
    int nscat = (2 * E0 + t2 + 255) / 256;
    int ngemm = H1 * (Mpad / 64);
    k1_scatter_gemm1<<<nscat + ngemm, 256, 0, stream>>>(
        edges, E0, W2, t2, nscat, (const float4*)x, W1, a1, N, slabN);

    // ---- K2: L2-blocked softmax-agg + ELU (4x16 lane map, dedup'd) ----
    int nbp = (N + 3) / 4;
    agg_h8_sliced<<<4 * nbp, 256, 0, stream>>>(N, slabN);

    // ---- K3: layer-2 MFMA GEMM (one wave/block) + fused alpha2 ----
    mfma_gemm2<<<(N + 15) / 16, 64, 0, stream>>>(a2, N);

    // ---- K4: layer-2 aggregation + g_cnt self-reset ----
    agg_node_h1<<<(N + 3) / 4, 256, 0, stream>>>((float*)d_out, N);
}